// Round 17
// baseline (68.213 us; speedup 1.0000x reference)
//
#include <hip/hip_runtime.h>

constexpr int NN = 10000;
constexpr int NE = 160000;
constexpr int D  = 512;
constexpr int KC = 8;      // wcomb split-K chunks (K=512 -> 8 x 64)
constexpr int MAXDEG = 96; // ELL width; mean deg 16

typedef __attribute__((ext_vector_type(8))) short short8;   // 8 bf16 (4 VGPRs)
typedef __attribute__((ext_vector_type(4))) float f32x4;    // MFMA C/D

static __device__ __forceinline__ ushort f2bf(float f) {
    union { float f; unsigned u; } v; v.f = f;
    unsigned r = (v.u + 0x7FFFu + ((v.u >> 16) & 1u)) >> 16;   // RNE
    return (ushort)r;
}

typedef __attribute__((address_space(3))) unsigned int lds_uint;
typedef const __attribute__((address_space(1))) unsigned int glb_uint;
static __device__ __forceinline__ void gload16(const ushort* g, ushort* l) {
    __builtin_amdgcn_global_load_lds((glb_uint*)g, (lds_uint*)l, 16, 0, 0);
}

// ---------------------------------------------------------------------------
// prep1: blocks [0,1344) wcomb split-K partials | [1344,1600) W2 transpose |
//        [1600,1640) zero deg.  (verified R10)
// ---------------------------------------------------------------------------
__global__ __launch_bounds__(256)
void prep1_kernel(const float* __restrict__ We, const float* __restrict__ be,
                  const float* __restrict__ W1, const float* __restrict__ W2,
                  float* __restrict__ part, ushort* __restrict__ W2t,
                  int* __restrict__ deg) {
    __shared__ float tile[32][33];
    const int b   = blockIdx.x;
    const int tid = threadIdx.x;

    if (b < 1344) {
        const int c  = (b & 7) * 64 + (tid & 63);
        const int r  = ((b >> 3) % 21) * 4 + (tid >> 6);
        const int kc = b / 168;
        if (r > 80) return;
        const float* arow = (r < 80) ? (We + (size_t)r * D) : be;
        const int k0 = kc * 64;
        float s = 0.f;
        #pragma unroll
        for (int k = 0; k < 64; k += 4) {
            float4 a = *reinterpret_cast<const float4*>(&arow[k0 + k]);
            s += a.x * W1[(size_t)(k0 + k    ) * D + c];
            s += a.y * W1[(size_t)(k0 + k + 1) * D + c];
            s += a.z * W1[(size_t)(k0 + k + 2) * D + c];
            s += a.w * W1[(size_t)(k0 + k + 3) * D + c];
        }
        part[((size_t)kc * 81 + r) * D + c] = s;
    } else if (b < 1600) {
        const int t  = b - 1344;
        const int bx = (t & 15) * 32;
        const int by = (t >> 4) * 32;
        const int tx = tid & 31;
        const int ty = tid >> 5;
        #pragma unroll
        for (int i = 0; i < 4; ++i)
            tile[ty + 8 * i][tx] = W2[(size_t)(by + ty + 8 * i) * D + bx + tx];
        __syncthreads();
        #pragma unroll
        for (int i = 0; i < 4; ++i)
            W2t[(size_t)(bx + ty + 8 * i) * D + by + tx] = f2bf(tile[tx][ty + 8 * i]);
    } else {
        const int i = (b - 1600) * 256 + tid;
        if (i < NN) deg[i] = 0;
    }
}

// ---------------------------------------------------------------------------
// prep2: blocks [0,256) wcomb_reduce -> WcT | [256,881) fill_ell  (verified)
// ---------------------------------------------------------------------------
__global__ __launch_bounds__(256)
void prep2_kernel(const float* __restrict__ part, const int* __restrict__ row,
                  ushort* __restrict__ WcT, int* __restrict__ deg,
                  int* __restrict__ ell) {
    const int b   = blockIdx.x;
    const int tid = threadIdx.x;
    if (b < 256) {
        const int i = b * 256 + tid;
        const int k = i >> 9;
        const int c = i & 511;
        float s = 0.f;
        if (k <= 80) {
            #pragma unroll
            for (int kc = 0; kc < KC; ++kc)
                s += part[((size_t)kc * 81 + k) * D + c];
        }
        WcT[(size_t)c * 128 + k] = f2bf(s);
    } else {
        const int e = (b - 256) * 256 + tid;
        if (e < NE) {
            int r = row[e];
            int slot = atomicAdd(&deg[r], 1);
            if (slot < MAXDEG) ell[r * MAXDEG + slot] = e;
        }
    }
}

// ---------------------------------------------------------------------------
// gather: one wave per node -> bf16 aggX[n][128]  (verified R11)
//   cols 0..63 rbf sums, 64..79 ang sums, 80 = cnt, 81..127 = 0
// ---------------------------------------------------------------------------
__global__ __launch_bounds__(256)
void gather_agg_kernel(const int* __restrict__ deg, const int* __restrict__ ell,
                       const float* __restrict__ rbf, const float* __restrict__ ang,
                       ushort* __restrict__ aggX) {
    const int wv   = threadIdx.x >> 6;
    const int lane = threadIdx.x & 63;
    const int n    = blockIdx.x * 4 + wv;
    if (n >= NN) return;
    int d = deg[n];
    if (d > MAXDEG) d = MAXDEG;
    const int* en = ell + (size_t)n * MAXDEG;
    float s1 = 0.f, s2 = 0.f;
    int i = 0;
    for (; i + 8 <= d; i += 8) {
        int e[8];
        #pragma unroll
        for (int j = 0; j < 8; ++j) e[j] = en[i + j];
        float v[8];
        #pragma unroll
        for (int j = 0; j < 8; ++j) v[j] = rbf[e[j] * 64 + lane];
        if (lane < 16) {
            #pragma unroll
            for (int j = 0; j < 8; ++j) s2 += ang[e[j] * 16 + lane];
        }
        #pragma unroll
        for (int j = 0; j < 8; ++j) s1 += v[j];
    }
    for (; i + 4 <= d; i += 4) {
        const int e0 = en[i], e1 = en[i + 1], e2 = en[i + 2], e3 = en[i + 3];
        const float v0 = rbf[e0 * 64 + lane];
        const float v1 = rbf[e1 * 64 + lane];
        const float v2 = rbf[e2 * 64 + lane];
        const float v3 = rbf[e3 * 64 + lane];
        if (lane < 16) {
            s2 += ang[e0 * 16 + lane] + ang[e1 * 16 + lane]
                + ang[e2 * 16 + lane] + ang[e3 * 16 + lane];
        }
        s1 += v0 + v1 + v2 + v3;
    }
    for (; i < d; ++i) {
        const int e = en[i];
        s1 += rbf[e * 64 + lane];
        if (lane < 16) s2 += ang[e * 16 + lane];
    }
    aggX[(size_t)n * 128 + lane] = f2bf(s1);
    const float v2 = (lane < 16) ? s2 : (lane == 16 ? (float)d : 0.f);
    aggX[(size_t)n * 128 + 64 + lane] = f2bf(v2);
}

// ---------------------------------------------------------------------------
// h1 MFMA (single K-tile, K=128): h1 = bf16(relu(aggX @ WcT^T + b1))
// 64x64 tile, grid 8 x 157 = 1256 (5 blocks/CU).  (verified R16)
// ---------------------------------------------------------------------------
__global__ __launch_bounds__(256)
void h1_mfma_kernel(const ushort* __restrict__ A, const ushort* __restrict__ Bt,
                    const float* __restrict__ b1, ushort* __restrict__ H, int M) {
    __shared__ ushort As[64 * 128];
    __shared__ ushort Bs[64 * 128];
    const int tid  = threadIdx.x;
    const int lane = tid & 63;
    const int wid  = tid >> 6;
    const int wm   = wid >> 1;
    const int wn   = wid & 1;

    const int l = blockIdx.y * gridDim.x + blockIdx.x;
    const int cpx = (gridDim.x * gridDim.y) >> 3;
    const int t_ = (l & 7) * cpx + (l >> 3);
    const int n0 = (t_ & 7) * 64;
    const int m0 = (t_ >> 3) * 64;

    const int r0 = tid >> 4;          // 0..15
    const int ch = tid & 15;          // 16B chunk 0..15

    f32x4 acc[2][2] = {};

    #pragma unroll
    for (int j = 0; j < 4; ++j) {
        const int r  = j * 16 + r0;
        const int gm = (m0 + r < M) ? (m0 + r) : (M - 1);
        const int cs = (ch ^ (r & 7)) * 8;
        const int rowbase = j * 16 + wid * 4;
        gload16(A + (size_t)gm * 128 + cs, &As[rowbase * 128]);
        gload16(Bt + (size_t)(n0 + r) * 128 + cs, &Bs[rowbase * 128]);
    }
    __syncthreads();

    #pragma unroll
    for (int kk = 0; kk < 4; ++kk) {
        const int kc = kk * 4 + (lane >> 4);
        short8 af[2], bfr[2];
        #pragma unroll
        for (int mf = 0; mf < 2; ++mf) {
            const int ar = wm * 32 + mf * 16 + (lane & 15);
            af[mf] = *reinterpret_cast<const short8*>(
                &As[ar * 128 + ((kc ^ (ar & 7)) * 8)]);
        }
        #pragma unroll
        for (int nf = 0; nf < 2; ++nf) {
            const int br = wn * 32 + nf * 16 + (lane & 15);
            bfr[nf] = *reinterpret_cast<const short8*>(
                &Bs[br * 128 + ((kc ^ (br & 7)) * 8)]);
        }
        #pragma unroll
        for (int mf = 0; mf < 2; ++mf)
            #pragma unroll
            for (int nf = 0; nf < 2; ++nf)
                acc[mf][nf] = __builtin_amdgcn_mfma_f32_16x16x32_bf16(
                    af[mf], bfr[nf], acc[mf][nf], 0, 0, 0);
    }

    #pragma unroll
    for (int mf = 0; mf < 2; ++mf) {
        const int rowb = m0 + wm * 32 + mf * 16 + ((lane >> 4) << 2);
        #pragma unroll
        for (int nf = 0; nf < 2; ++nf) {
            const int col = n0 + wn * 32 + nf * 16 + (lane & 15);
            const float bv = b1[col];
            #pragma unroll
            for (int r = 0; r < 4; ++r) {
                const int row = rowb + r;
                if (row < M)
                    H[(size_t)row * D + col] = f2bf(fmaxf(acc[mf][nf][r] + bv, 0.f));
            }
        }
    }
}

// ---------------------------------------------------------------------------
// out MFMA: out = h1 @ W2t^T + b2 + x   (f32 out)
// R17: 2-deep counted-vmcnt pipeline (raw s_barrier + vmcnt(6)), replacing
// the __syncthreads vmcnt(0) drain that exposed load latency every k-tile.
// Schedule (uniform across waves; each wave waits only its OWN 6 stage
// loads, barrier then guarantees the whole buffer):
//   xpf; stage(0,t0); stage(1,t1); vmcnt(6); bar
//   for t: MFMA(buf t&1); bar; [stage(t&1,t+2); vmcnt(6) | vmcnt(0)]; bar
// ---------------------------------------------------------------------------
__global__ __launch_bounds__(256)
void mfma_gemm_kernel(const ushort* __restrict__ A, const ushort* __restrict__ Bt,
                      const float* __restrict__ bias, const float* __restrict__ xres,
                      float* __restrict__ Cout, int M) {
    __shared__ ushort As[2][128 * 64];
    __shared__ ushort Bs[2][64 * 64];
    const int tid  = threadIdx.x;
    const int lane = tid & 63;
    const int wid  = tid >> 6;

    const int l = blockIdx.y * gridDim.x + blockIdx.x;
    const int cpx = (gridDim.x * gridDim.y) >> 3;
    const int t_ = (l & 7) * cpx + (l >> 3);
    const int n0 = (t_ & 7) * 64;
    const int m0 = (t_ >> 3) * 128;

    const int sr = lane >> 3;
    const int sc = lane & 7;

    f32x4 acc[2][4] = {};
    constexpr int KTILES = D / 64;

    auto stage = [&](int buf, int t) {   // 6 vmem ops per wave
        #pragma unroll
        for (int j = 0; j < 4; ++j) {
            const int r  = wid * 32 + j * 8 + sr;
            const int gm = (m0 + r < M) ? (m0 + r) : (M - 1);
            const int cs = (sc ^ (r & 7)) * 8;
            const int rowbase = wid * 32 + j * 8;
            gload16(A + (size_t)gm * D + t * 64 + cs, &As[buf][rowbase * 64]);
        }
        #pragma unroll
        for (int j = 0; j < 2; ++j) {
            const int r  = wid * 16 + j * 8 + sr;
            const int cs = (sc ^ (r & 7)) * 8;
            const int rowbase = wid * 16 + j * 8;
            gload16(Bt + (size_t)(n0 + r) * D + t * 64 + cs, &Bs[buf][rowbase * 64]);
        }
    };

    // x-residual prefetch, issued FIRST (FIFO: drained by the prologue
    // vmcnt(6) together with stage t0; hides under the whole K-loop).
    float xv[2][4][4];
    #pragma unroll
    for (int mf = 0; mf < 2; ++mf) {
        const int rowb = m0 + wid * 32 + mf * 16 + ((lane >> 4) << 2);
        #pragma unroll
        for (int nf = 0; nf < 4; ++nf) {
            const int col = n0 + nf * 16 + (lane & 15);
            #pragma unroll
            for (int r = 0; r < 4; ++r) {
                const int row = (rowb + r < M) ? (rowb + r) : (M - 1);
                xv[mf][nf][r] = xres[(size_t)row * D + col];
            }
        }
    }

    stage(0, 0);
    stage(1, 1);
    asm volatile("s_waitcnt vmcnt(6)" ::: "memory");   // xpf + t0 done; t1 in flight
    __builtin_amdgcn_sched_barrier(0);
    __builtin_amdgcn_s_barrier();                      // all waves: buf0 staged

    for (int t = 0; t < KTILES; ++t) {
        const int cur = t & 1;
        #pragma unroll
        for (int kk = 0; kk < 2; ++kk) {
            const int kc = kk * 4 + (lane >> 4);
            short8 af[2], bfr[4];
            #pragma unroll
            for (int mf = 0; mf < 2; ++mf) {
                const int ar = wid * 32 + mf * 16 + (lane & 15);
                af[mf] = *reinterpret_cast<const short8*>(
                    &As[cur][ar * 64 + ((kc ^ (ar & 7)) * 8)]);
            }
            #pragma unroll
            for (int nf = 0; nf < 4; ++nf) {
                const int br = nf * 16 + (lane & 15);
                bfr[nf] = *reinterpret_cast<const short8*>(
                    &Bs[cur][br * 64 + ((kc ^ (br & 7)) * 8)]);
            }
            #pragma unroll
            for (int mf = 0; mf < 2; ++mf)
                #pragma unroll
                for (int nf = 0; nf < 4; ++nf)
                    acc[mf][nf] = __builtin_amdgcn_mfma_f32_16x16x32_bf16(
                        af[mf], bfr[nf], acc[mf][nf], 0, 0, 0);
        }
        if (t + 1 < KTILES) {
            __builtin_amdgcn_s_barrier();   // all waves done READING buf[cur]
            if (t + 2 < KTILES) {
                stage(cur, t + 2);          // restage freed buffer
                asm volatile("s_waitcnt vmcnt(6)" ::: "memory");  // own t+1 done
            } else {
                asm volatile("s_waitcnt vmcnt(0)" ::: "memory");  // own t+1 done
            }
            __builtin_amdgcn_sched_barrier(0);
            __builtin_amdgcn_s_barrier();   // all waves: buf[t+1] fully staged
        }
    }

    #pragma unroll
    for (int mf = 0; mf < 2; ++mf) {
        const int rowb = m0 + wid * 32 + mf * 16 + ((lane >> 4) << 2);
        #pragma unroll
        for (int nf = 0; nf < 4; ++nf) {
            const int col = n0 + nf * 16 + (lane & 15);
            const float bv = bias[col];
            #pragma unroll
            for (int r = 0; r < 4; ++r) {
                const int row = rowb + r;
                if (row < M)
                    Cout[(size_t)row * D + col] =
                        acc[mf][nf][r] + bv + xv[mf][nf][r];
            }
        }
    }
}

extern "C" void kernel_launch(void* const* d_in, const int* in_sizes, int n_in,
                              void* d_out, int out_size, void* d_ws, size_t ws_size,
                              hipStream_t stream) {
    const float* x      = (const float*)d_in[0];
    const int*   edge_index = (const int*)d_in[2];
    const float* rbf    = (const float*)d_in[3];
    const float* ang    = (const float*)d_in[4];
    const float* W_edge = (const float*)d_in[5];
    const float* b_edge = (const float*)d_in[6];
    const float* W1     = (const float*)d_in[7];
    const float* b1     = (const float*)d_in[8];
    const float* W2     = (const float*)d_in[9];
    const float* b2     = (const float*)d_in[10];
    float* out = (float*)d_out;

    char* w = (char*)d_ws;
    ushort* aggX = (ushort*)w;                       //  2,560,000 B [NN][128]
    ushort* W2t  = (ushort*)(w + 2560000);           //    524,288 B
    ushort* WcT  = (ushort*)(w + 3084288);           //    131,072 B [512][128]
    int*    deg  = (int*)(w + 3215360);              //     40,000 B
    float*  part = (float*)(w + 3255360);            //  1,327,104 B
    int*    ell  = (int*)(w + 4582464);              //  3,840,000 B
    ushort* h1   = (ushort*)(w + 3255360);           // 10,240,000 B (aliases part+ell)

    prep1_kernel<<<1640, 256, 0, stream>>>(W_edge, b_edge, W1, W2, part, W2t, deg);
    prep2_kernel<<<881, 256, 0, stream>>>(part, edge_index, WcT, deg, ell);
    gather_agg_kernel<<<NN / 4, 256, 0, stream>>>(deg, ell, rbf, ang, aggX);

    dim3 hgrid(D / 64, (NN + 63) / 64);     // 8 x 157 = 1256 blocks, %8==0
    h1_mfma_kernel<<<hgrid, 256, 0, stream>>>(aggX, WcT, b1, h1, NN);

    dim3 ggrid(D / 64, (NN + 127) / 128);   // 8 x 79 = 632 blocks, %8==0
    mfma_gemm_kernel<<<ggrid, 256, 0, stream>>>(h1, W2t, b2, x, out, NN);
}

// Round 18
// 66.131 us; speedup vs baseline: 1.0315x; 1.0315x over previous
//
#include <hip/hip_runtime.h>

constexpr int NN = 10000;
constexpr int NE = 160000;
constexpr int D  = 512;
constexpr int KC = 8;      // wcomb split-K chunks (K=512 -> 8 x 64)
constexpr int MAXDEG = 96; // ELL width; mean deg 16

typedef __attribute__((ext_vector_type(8))) short short8;   // 8 bf16 (4 VGPRs)
typedef __attribute__((ext_vector_type(4))) float f32x4;    // MFMA C/D

static __device__ __forceinline__ ushort f2bf(float f) {
    union { float f; unsigned u; } v; v.f = f;
    unsigned r = (v.u + 0x7FFFu + ((v.u >> 16) & 1u)) >> 16;   // RNE
    return (ushort)r;
}

typedef __attribute__((address_space(3))) unsigned int lds_uint;
typedef const __attribute__((address_space(1))) unsigned int glb_uint;
static __device__ __forceinline__ void gload16(const ushort* g, ushort* l) {
    __builtin_amdgcn_global_load_lds((glb_uint*)g, (lds_uint*)l, 16, 0, 0);
}

// ---------------------------------------------------------------------------
// prep1: blocks [0,1344) wcomb split-K partials | [1344,1600) W2 transpose |
//        [1600,1640) zero deg.  (verified R10)
// ---------------------------------------------------------------------------
__global__ __launch_bounds__(256)
void prep1_kernel(const float* __restrict__ We, const float* __restrict__ be,
                  const float* __restrict__ W1, const float* __restrict__ W2,
                  float* __restrict__ part, ushort* __restrict__ W2t,
                  int* __restrict__ deg) {
    __shared__ float tile[32][33];
    const int b   = blockIdx.x;
    const int tid = threadIdx.x;

    if (b < 1344) {
        const int c  = (b & 7) * 64 + (tid & 63);
        const int r  = ((b >> 3) % 21) * 4 + (tid >> 6);
        const int kc = b / 168;
        if (r > 80) return;
        const float* arow = (r < 80) ? (We + (size_t)r * D) : be;
        const int k0 = kc * 64;
        float s = 0.f;
        #pragma unroll
        for (int k = 0; k < 64; k += 4) {
            float4 a = *reinterpret_cast<const float4*>(&arow[k0 + k]);
            s += a.x * W1[(size_t)(k0 + k    ) * D + c];
            s += a.y * W1[(size_t)(k0 + k + 1) * D + c];
            s += a.z * W1[(size_t)(k0 + k + 2) * D + c];
            s += a.w * W1[(size_t)(k0 + k + 3) * D + c];
        }
        part[((size_t)kc * 81 + r) * D + c] = s;
    } else if (b < 1600) {
        const int t  = b - 1344;
        const int bx = (t & 15) * 32;
        const int by = (t >> 4) * 32;
        const int tx = tid & 31;
        const int ty = tid >> 5;
        #pragma unroll
        for (int i = 0; i < 4; ++i)
            tile[ty + 8 * i][tx] = W2[(size_t)(by + ty + 8 * i) * D + bx + tx];
        __syncthreads();
        #pragma unroll
        for (int i = 0; i < 4; ++i)
            W2t[(size_t)(bx + ty + 8 * i) * D + by + tx] = f2bf(tile[tx][ty + 8 * i]);
    } else {
        const int i = (b - 1600) * 256 + tid;
        if (i < NN) deg[i] = 0;
    }
}

// ---------------------------------------------------------------------------
// prep2: blocks [0,256) wcomb_reduce -> WcT | [256,881) fill_ell  (verified)
// ---------------------------------------------------------------------------
__global__ __launch_bounds__(256)
void prep2_kernel(const float* __restrict__ part, const int* __restrict__ row,
                  ushort* __restrict__ WcT, int* __restrict__ deg,
                  int* __restrict__ ell) {
    const int b   = blockIdx.x;
    const int tid = threadIdx.x;
    if (b < 256) {
        const int i = b * 256 + tid;
        const int k = i >> 9;
        const int c = i & 511;
        float s = 0.f;
        if (k <= 80) {
            #pragma unroll
            for (int kc = 0; kc < KC; ++kc)
                s += part[((size_t)kc * 81 + k) * D + c];
        }
        WcT[(size_t)c * 128 + k] = f2bf(s);
    } else {
        const int e = (b - 256) * 256 + tid;
        if (e < NE) {
            int r = row[e];
            int slot = atomicAdd(&deg[r], 1);
            if (slot < MAXDEG) ell[r * MAXDEG + slot] = e;
        }
    }
}

// ---------------------------------------------------------------------------
// gather: one wave per node -> bf16 aggX[n][128]  (verified R11)
//   cols 0..63 rbf sums, 64..79 ang sums, 80 = cnt, 81..127 = 0
// ---------------------------------------------------------------------------
__global__ __launch_bounds__(256)
void gather_agg_kernel(const int* __restrict__ deg, const int* __restrict__ ell,
                       const float* __restrict__ rbf, const float* __restrict__ ang,
                       ushort* __restrict__ aggX) {
    const int wv   = threadIdx.x >> 6;
    const int lane = threadIdx.x & 63;
    const int n    = blockIdx.x * 4 + wv;
    if (n >= NN) return;
    int d = deg[n];
    if (d > MAXDEG) d = MAXDEG;
    const int* en = ell + (size_t)n * MAXDEG;
    float s1 = 0.f, s2 = 0.f;
    int i = 0;
    for (; i + 8 <= d; i += 8) {
        int e[8];
        #pragma unroll
        for (int j = 0; j < 8; ++j) e[j] = en[i + j];
        float v[8];
        #pragma unroll
        for (int j = 0; j < 8; ++j) v[j] = rbf[e[j] * 64 + lane];
        if (lane < 16) {
            #pragma unroll
            for (int j = 0; j < 8; ++j) s2 += ang[e[j] * 16 + lane];
        }
        #pragma unroll
        for (int j = 0; j < 8; ++j) s1 += v[j];
    }
    for (; i + 4 <= d; i += 4) {
        const int e0 = en[i], e1 = en[i + 1], e2 = en[i + 2], e3 = en[i + 3];
        const float v0 = rbf[e0 * 64 + lane];
        const float v1 = rbf[e1 * 64 + lane];
        const float v2 = rbf[e2 * 64 + lane];
        const float v3 = rbf[e3 * 64 + lane];
        if (lane < 16) {
            s2 += ang[e0 * 16 + lane] + ang[e1 * 16 + lane]
                + ang[e2 * 16 + lane] + ang[e3 * 16 + lane];
        }
        s1 += v0 + v1 + v2 + v3;
    }
    for (; i < d; ++i) {
        const int e = en[i];
        s1 += rbf[e * 64 + lane];
        if (lane < 16) s2 += ang[e * 16 + lane];
    }
    aggX[(size_t)n * 128 + lane] = f2bf(s1);
    const float v2 = (lane < 16) ? s2 : (lane == 16 ? (float)d : 0.f);
    aggX[(size_t)n * 128 + 64 + lane] = f2bf(v2);
}

// ---------------------------------------------------------------------------
// h1 MFMA (single K-tile, K=128): h1 = bf16(relu(aggX @ WcT^T + b1))
// 64x64 tile, grid 8 x 157 = 1256.  (verified R16)
// ---------------------------------------------------------------------------
__global__ __launch_bounds__(256)
void h1_mfma_kernel(const ushort* __restrict__ A, const ushort* __restrict__ Bt,
                    const float* __restrict__ b1, ushort* __restrict__ H, int M) {
    __shared__ ushort As[64 * 128];
    __shared__ ushort Bs[64 * 128];
    const int tid  = threadIdx.x;
    const int lane = tid & 63;
    const int wid  = tid >> 6;
    const int wm   = wid >> 1;
    const int wn   = wid & 1;

    const int l = blockIdx.y * gridDim.x + blockIdx.x;
    const int cpx = (gridDim.x * gridDim.y) >> 3;
    const int t_ = (l & 7) * cpx + (l >> 3);
    const int n0 = (t_ & 7) * 64;
    const int m0 = (t_ >> 3) * 64;

    const int r0 = tid >> 4;          // 0..15
    const int ch = tid & 15;          // 16B chunk 0..15

    f32x4 acc[2][2] = {};

    #pragma unroll
    for (int j = 0; j < 4; ++j) {
        const int r  = j * 16 + r0;
        const int gm = (m0 + r < M) ? (m0 + r) : (M - 1);
        const int cs = (ch ^ (r & 7)) * 8;
        const int rowbase = j * 16 + wid * 4;
        gload16(A + (size_t)gm * 128 + cs, &As[rowbase * 128]);
        gload16(Bt + (size_t)(n0 + r) * 128 + cs, &Bs[rowbase * 128]);
    }
    __syncthreads();

    #pragma unroll
    for (int kk = 0; kk < 4; ++kk) {
        const int kc = kk * 4 + (lane >> 4);
        short8 af[2], bfr[2];
        #pragma unroll
        for (int mf = 0; mf < 2; ++mf) {
            const int ar = wm * 32 + mf * 16 + (lane & 15);
            af[mf] = *reinterpret_cast<const short8*>(
                &As[ar * 128 + ((kc ^ (ar & 7)) * 8)]);
        }
        #pragma unroll
        for (int nf = 0; nf < 2; ++nf) {
            const int br = wn * 32 + nf * 16 + (lane & 15);
            bfr[nf] = *reinterpret_cast<const short8*>(
                &Bs[br * 128 + ((kc ^ (br & 7)) * 8)]);
        }
        #pragma unroll
        for (int mf = 0; mf < 2; ++mf)
            #pragma unroll
            for (int nf = 0; nf < 2; ++nf)
                acc[mf][nf] = __builtin_amdgcn_mfma_f32_16x16x32_bf16(
                    af[mf], bfr[nf], acc[mf][nf], 0, 0, 0);
    }

    #pragma unroll
    for (int mf = 0; mf < 2; ++mf) {
        const int rowb = m0 + wm * 32 + mf * 16 + ((lane >> 4) << 2);
        #pragma unroll
        for (int nf = 0; nf < 2; ++nf) {
            const int col = n0 + wn * 32 + nf * 16 + (lane & 15);
            const float bv = b1[col];
            #pragma unroll
            for (int r = 0; r < 4; ++r) {
                const int row = rowb + r;
                if (row < M)
                    H[(size_t)row * D + col] = f2bf(fmaxf(acc[mf][nf][r] + bv, 0.f));
            }
        }
    }
}

// ---------------------------------------------------------------------------
// out MFMA: out = h1 @ W2t^T + b2 + x   (f32 out)
// R18: 512 threads / 8 waves per block (4m x 2n, each wave 32x32 of the
// 128x64 tile). Same grid 632, same LDS 48KB, same staged bytes -- but
// 19.75 waves/CU vs 9.9: out was wave-starved (R17 counted-vmcnt null =>
// latency must be hidden by TLP, not intra-wave schedule).
// 2-phase __syncthreads pipeline (R15-verified), x reg-prefetch.
// ---------------------------------------------------------------------------
__global__ __launch_bounds__(512)
void mfma_gemm_kernel(const ushort* __restrict__ A, const ushort* __restrict__ Bt,
                      const float* __restrict__ bias, const float* __restrict__ xres,
                      float* __restrict__ Cout, int M) {
    __shared__ ushort As[2][128 * 64];
    __shared__ ushort Bs[2][64 * 64];
    const int tid  = threadIdx.x;
    const int lane = tid & 63;
    const int wid  = tid >> 6;        // 0..7
    const int wm   = wid >> 1;        // 0..3 (32-row span)
    const int wn   = wid & 1;         // 0..1 (32-col span)

    const int l = blockIdx.y * gridDim.x + blockIdx.x;
    const int cpx = (gridDim.x * gridDim.y) >> 3;
    const int t_ = (l & 7) * cpx + (l >> 3);
    const int n0 = (t_ & 7) * 64;
    const int m0 = (t_ >> 3) * 128;

    const int sr = lane >> 3;         // 0..7
    const int sc = lane & 7;          // chunk 0..7

    f32x4 acc[2][2] = {};
    constexpr int KTILES = D / 64;

    auto stage = [&](int buf, int t) {   // 3 gloads per wave
        #pragma unroll
        for (int j = 0; j < 2; ++j) {    // A: wave rows [wid*16, +16)
            const int r  = wid * 16 + j * 8 + sr;
            const int gm = (m0 + r < M) ? (m0 + r) : (M - 1);
            const int cs = (sc ^ (r & 7)) * 8;
            const int rowbase = wid * 16 + j * 8;
            gload16(A + (size_t)gm * D + t * 64 + cs, &As[buf][rowbase * 64]);
        }
        {                                // B: wave rows [wid*8, +8)
            const int r  = wid * 8 + sr;
            const int cs = (sc ^ (r & 7)) * 8;
            const int rowbase = wid * 8;
            gload16(Bt + (size_t)(n0 + r) * D + t * 64 + cs, &Bs[buf][rowbase * 64]);
        }
    };

    stage(0, 0);

    // x-residual prefetch (independent; hides under the K-loop)
    float xv[2][2][4];
    #pragma unroll
    for (int mf = 0; mf < 2; ++mf) {
        const int rowb = m0 + wm * 32 + mf * 16 + ((lane >> 4) << 2);
        #pragma unroll
        for (int nf = 0; nf < 2; ++nf) {
            const int col = n0 + wn * 32 + nf * 16 + (lane & 15);
            #pragma unroll
            for (int r = 0; r < 4; ++r) {
                const int row = (rowb + r < M) ? (rowb + r) : (M - 1);
                xv[mf][nf][r] = xres[(size_t)row * D + col];
            }
        }
    }

    __syncthreads();

    for (int t = 0; t < KTILES; ++t) {
        const int cur = t & 1;
        if (t + 1 < KTILES) stage(cur ^ 1, t + 1);
        #pragma unroll
        for (int kk = 0; kk < 2; ++kk) {
            const int kc = kk * 4 + (lane >> 4);
            short8 af[2], bfr[2];
            #pragma unroll
            for (int mf = 0; mf < 2; ++mf) {
                const int ar = wm * 32 + mf * 16 + (lane & 15);
                af[mf] = *reinterpret_cast<const short8*>(
                    &As[cur][ar * 64 + ((kc ^ (ar & 7)) * 8)]);
            }
            #pragma unroll
            for (int nf = 0; nf < 2; ++nf) {
                const int br = wn * 32 + nf * 16 + (lane & 15);
                bfr[nf] = *reinterpret_cast<const short8*>(
                    &Bs[cur][br * 64 + ((kc ^ (br & 7)) * 8)]);
            }
            #pragma unroll
            for (int mf = 0; mf < 2; ++mf)
                #pragma unroll
                for (int nf = 0; nf < 2; ++nf)
                    acc[mf][nf] = __builtin_amdgcn_mfma_f32_16x16x32_bf16(
                        af[mf], bfr[nf], acc[mf][nf], 0, 0, 0);
        }
        __syncthreads();
    }

    #pragma unroll
    for (int mf = 0; mf < 2; ++mf) {
        const int rowb = m0 + wm * 32 + mf * 16 + ((lane >> 4) << 2);
        #pragma unroll
        for (int nf = 0; nf < 2; ++nf) {
            const int col = n0 + wn * 32 + nf * 16 + (lane & 15);
            const float bv = bias[col];
            #pragma unroll
            for (int r = 0; r < 4; ++r) {
                const int row = rowb + r;
                if (row < M)
                    Cout[(size_t)row * D + col] =
                        acc[mf][nf][r] + bv + xv[mf][nf][r];
            }
        }
    }
}

extern "C" void kernel_launch(void* const* d_in, const int* in_sizes, int n_in,
                              void* d_out, int out_size, void* d_ws, size_t ws_size,
                              hipStream_t stream) {
    const float* x      = (const float*)d_in[0];
    const int*   edge_index = (const int*)d_in[2];
    const float* rbf    = (const float*)d_in[3];
    const float* ang    = (const float*)d_in[4];
    const float* W_edge = (const float*)d_in[5];
    const float* b_edge = (const float*)d_in[6];
    const float* W1     = (const float*)d_in[7];
    const float* b1     = (const float*)d_in[8];
    const float* W2     = (const float*)d_in[9];
    const float* b2     = (const float*)d_in[10];
    float* out = (float*)d_out;

    char* w = (char*)d_ws;
    ushort* aggX = (ushort*)w;                       //  2,560,000 B [NN][128]
    ushort* W2t  = (ushort*)(w + 2560000);           //    524,288 B
    ushort* WcT  = (ushort*)(w + 3084288);           //    131,072 B [512][128]
    int*    deg  = (int*)(w + 3215360);              //     40,000 B
    float*  part = (float*)(w + 3255360);            //  1,327,104 B
    int*    ell  = (int*)(w + 4582464);              //  3,840,000 B
    ushort* h1   = (ushort*)(w + 3255360);           // 10,240,000 B (aliases part+ell)

    prep1_kernel<<<1640, 256, 0, stream>>>(W_edge, b_edge, W1, W2, part, W2t, deg);
    prep2_kernel<<<881, 256, 0, stream>>>(part, edge_index, WcT, deg, ell);
    gather_agg_kernel<<<NN / 4, 256, 0, stream>>>(deg, ell, rbf, ang, aggX);

    dim3 hgrid(D / 64, (NN + 63) / 64);     // 8 x 157 = 1256 blocks, %8==0
    h1_mfma_kernel<<<hgrid, 256, 0, stream>>>(aggX, WcT, b1, h1, NN);

    dim3 ggrid(D / 64, (NN + 127) / 128);   // 8 x 79 = 632 blocks, %8==0
    mfma_gemm_kernel<<<ggrid, 512, 0, stream>>>(h1, W2t, b2, x, out, NN);
}

// Round 19
// 64.347 us; speedup vs baseline: 1.0601x; 1.0277x over previous
//
#include <hip/hip_runtime.h>

constexpr int NN = 10000;
constexpr int NE = 160000;
constexpr int D  = 512;
constexpr int KC = 8;      // wcomb split-K chunks (K=512 -> 8 x 64)
constexpr int MAXDEG = 96; // ELL width; mean deg 16

typedef __attribute__((ext_vector_type(8))) short short8;   // 8 bf16 (4 VGPRs)
typedef __attribute__((ext_vector_type(4))) float f32x4;    // MFMA C/D

static __device__ __forceinline__ ushort f2bf(float f) {
    union { float f; unsigned u; } v; v.f = f;
    unsigned r = (v.u + 0x7FFFu + ((v.u >> 16) & 1u)) >> 16;   // RNE
    return (ushort)r;
}

typedef __attribute__((address_space(3))) unsigned int lds_uint;
typedef const __attribute__((address_space(1))) unsigned int glb_uint;
static __device__ __forceinline__ void gload16(const ushort* g, ushort* l) {
    __builtin_amdgcn_global_load_lds((glb_uint*)g, (lds_uint*)l, 16, 0, 0);
}

// ---------------------------------------------------------------------------
// prep1: blocks [0,1344) wcomb split-K partials | [1344,1600) W2 transpose |
//        [1600,1640) zero deg.  (verified R10)
// ---------------------------------------------------------------------------
__global__ __launch_bounds__(256)
void prep1_kernel(const float* __restrict__ We, const float* __restrict__ be,
                  const float* __restrict__ W1, const float* __restrict__ W2,
                  float* __restrict__ part, ushort* __restrict__ W2t,
                  int* __restrict__ deg) {
    __shared__ float tile[32][33];
    const int b   = blockIdx.x;
    const int tid = threadIdx.x;

    if (b < 1344) {
        const int c  = (b & 7) * 64 + (tid & 63);
        const int r  = ((b >> 3) % 21) * 4 + (tid >> 6);
        const int kc = b / 168;
        if (r > 80) return;
        const float* arow = (r < 80) ? (We + (size_t)r * D) : be;
        const int k0 = kc * 64;
        float s = 0.f;
        #pragma unroll
        for (int k = 0; k < 64; k += 4) {
            float4 a = *reinterpret_cast<const float4*>(&arow[k0 + k]);
            s += a.x * W1[(size_t)(k0 + k    ) * D + c];
            s += a.y * W1[(size_t)(k0 + k + 1) * D + c];
            s += a.z * W1[(size_t)(k0 + k + 2) * D + c];
            s += a.w * W1[(size_t)(k0 + k + 3) * D + c];
        }
        part[((size_t)kc * 81 + r) * D + c] = s;
    } else if (b < 1600) {
        const int t  = b - 1344;
        const int bx = (t & 15) * 32;
        const int by = (t >> 4) * 32;
        const int tx = tid & 31;
        const int ty = tid >> 5;
        #pragma unroll
        for (int i = 0; i < 4; ++i)
            tile[ty + 8 * i][tx] = W2[(size_t)(by + ty + 8 * i) * D + bx + tx];
        __syncthreads();
        #pragma unroll
        for (int i = 0; i < 4; ++i)
            W2t[(size_t)(bx + ty + 8 * i) * D + by + tx] = f2bf(tile[tx][ty + 8 * i]);
    } else {
        const int i = (b - 1600) * 256 + tid;
        if (i < NN) deg[i] = 0;
    }
}

// ---------------------------------------------------------------------------
// prep2: blocks [0,256) wcomb_reduce -> WcT | [256,881) fill_ell  (verified)
// ---------------------------------------------------------------------------
__global__ __launch_bounds__(256)
void prep2_kernel(const float* __restrict__ part, const int* __restrict__ row,
                  ushort* __restrict__ WcT, int* __restrict__ deg,
                  int* __restrict__ ell) {
    const int b   = blockIdx.x;
    const int tid = threadIdx.x;
    if (b < 256) {
        const int i = b * 256 + tid;
        const int k = i >> 9;
        const int c = i & 511;
        float s = 0.f;
        if (k <= 80) {
            #pragma unroll
            for (int kc = 0; kc < KC; ++kc)
                s += part[((size_t)kc * 81 + k) * D + c];
        }
        WcT[(size_t)c * 128 + k] = f2bf(s);
    } else {
        const int e = (b - 256) * 256 + tid;
        if (e < NE) {
            int r = row[e];
            int slot = atomicAdd(&deg[r], 1);
            if (slot < MAXDEG) ell[r * MAXDEG + slot] = e;
        }
    }
}

// ---------------------------------------------------------------------------
// gather: one wave per node -> bf16 aggX[n][128]  (verified R11)
//   cols 0..63 rbf sums, 64..79 ang sums, 80 = cnt, 81..127 = 0
// ---------------------------------------------------------------------------
__global__ __launch_bounds__(256)
void gather_agg_kernel(const int* __restrict__ deg, const int* __restrict__ ell,
                       const float* __restrict__ rbf, const float* __restrict__ ang,
                       ushort* __restrict__ aggX) {
    const int wv   = threadIdx.x >> 6;
    const int lane = threadIdx.x & 63;
    const int n    = blockIdx.x * 4 + wv;
    if (n >= NN) return;
    int d = deg[n];
    if (d > MAXDEG) d = MAXDEG;
    const int* en = ell + (size_t)n * MAXDEG;
    float s1 = 0.f, s2 = 0.f;
    int i = 0;
    for (; i + 8 <= d; i += 8) {
        int e[8];
        #pragma unroll
        for (int j = 0; j < 8; ++j) e[j] = en[i + j];
        float v[8];
        #pragma unroll
        for (int j = 0; j < 8; ++j) v[j] = rbf[e[j] * 64 + lane];
        if (lane < 16) {
            #pragma unroll
            for (int j = 0; j < 8; ++j) s2 += ang[e[j] * 16 + lane];
        }
        #pragma unroll
        for (int j = 0; j < 8; ++j) s1 += v[j];
    }
    for (; i + 4 <= d; i += 4) {
        const int e0 = en[i], e1 = en[i + 1], e2 = en[i + 2], e3 = en[i + 3];
        const float v0 = rbf[e0 * 64 + lane];
        const float v1 = rbf[e1 * 64 + lane];
        const float v2 = rbf[e2 * 64 + lane];
        const float v3 = rbf[e3 * 64 + lane];
        if (lane < 16) {
            s2 += ang[e0 * 16 + lane] + ang[e1 * 16 + lane]
                + ang[e2 * 16 + lane] + ang[e3 * 16 + lane];
        }
        s1 += v0 + v1 + v2 + v3;
    }
    for (; i < d; ++i) {
        const int e = en[i];
        s1 += rbf[e * 64 + lane];
        if (lane < 16) s2 += ang[e * 16 + lane];
    }
    aggX[(size_t)n * 128 + lane] = f2bf(s1);
    const float v2 = (lane < 16) ? s2 : (lane == 16 ? (float)d : 0.f);
    aggX[(size_t)n * 128 + 64 + lane] = f2bf(v2);
}

// ---------------------------------------------------------------------------
// h1 MFMA (single K-tile, K=128): h1 = bf16(relu(aggX @ WcT^T + b1))
// R19: 512 threads / 8 waves (4m x 2n, each wave 32x32 of a 128x64 tile) --
// mirror of R18's out change. Grid 8 x 79 = 632, LDS 48KB -> 3 blocks/CU,
// 24 waves/CU (vs 20), staging issued by 8 waves.
// ---------------------------------------------------------------------------
__global__ __launch_bounds__(512)
void h1_mfma_kernel(const ushort* __restrict__ A, const ushort* __restrict__ Bt,
                    const float* __restrict__ b1, ushort* __restrict__ H, int M) {
    __shared__ ushort As[128 * 128];   // 32 KB
    __shared__ ushort Bs[64 * 128];    // 16 KB
    const int tid  = threadIdx.x;
    const int lane = tid & 63;
    const int wid  = tid >> 6;        // 0..7
    const int wm   = wid >> 1;        // 0..3
    const int wn   = wid & 1;         // 0..1

    const int l = blockIdx.y * gridDim.x + blockIdx.x;
    const int cpx = (gridDim.x * gridDim.y) >> 3;
    const int t_ = (l & 7) * cpx + (l >> 3);
    const int n0 = (t_ & 7) * 64;
    const int m0 = (t_ >> 3) * 128;

    const int rg = lane >> 4;         // 0..3 (4 rows per gload, 16 chunks/row)
    const int ch = lane & 15;         // 16B chunk 0..15

    f32x4 acc[2][2] = {};

    // A: wave rows [wid*16, +16) in 4 gloads of 4 rows
    #pragma unroll
    for (int j = 0; j < 4; ++j) {
        const int r  = wid * 16 + j * 4 + rg;
        const int gm = (m0 + r < M) ? (m0 + r) : (M - 1);
        const int cs = (ch ^ (r & 7)) * 8;
        const int rowbase = wid * 16 + j * 4;
        gload16(A + (size_t)gm * 128 + cs, &As[rowbase * 128]);
    }
    // B: wave rows [wid*8, +8) in 2 gloads
    #pragma unroll
    for (int j = 0; j < 2; ++j) {
        const int r  = wid * 8 + j * 4 + rg;
        const int cs = (ch ^ (r & 7)) * 8;
        const int rowbase = wid * 8 + j * 4;
        gload16(Bt + (size_t)(n0 + r) * 128 + cs, &Bs[rowbase * 128]);
    }
    __syncthreads();

    #pragma unroll
    for (int kk = 0; kk < 4; ++kk) {
        const int kc = kk * 4 + (lane >> 4);
        short8 af[2], bfr[2];
        #pragma unroll
        for (int mf = 0; mf < 2; ++mf) {
            const int ar = wm * 32 + mf * 16 + (lane & 15);
            af[mf] = *reinterpret_cast<const short8*>(
                &As[ar * 128 + ((kc ^ (ar & 7)) * 8)]);
        }
        #pragma unroll
        for (int nf = 0; nf < 2; ++nf) {
            const int br = wn * 32 + nf * 16 + (lane & 15);
            bfr[nf] = *reinterpret_cast<const short8*>(
                &Bs[br * 128 + ((kc ^ (br & 7)) * 8)]);
        }
        #pragma unroll
        for (int mf = 0; mf < 2; ++mf)
            #pragma unroll
            for (int nf = 0; nf < 2; ++nf)
                acc[mf][nf] = __builtin_amdgcn_mfma_f32_16x16x32_bf16(
                    af[mf], bfr[nf], acc[mf][nf], 0, 0, 0);
    }

    // C/D layout: col = lane&15, row = (lane>>4)*4 + reg  [m89]
    #pragma unroll
    for (int mf = 0; mf < 2; ++mf) {
        const int rowb = m0 + wm * 32 + mf * 16 + ((lane >> 4) << 2);
        #pragma unroll
        for (int nf = 0; nf < 2; ++nf) {
            const int col = n0 + wn * 32 + nf * 16 + (lane & 15);
            const float bv = b1[col];
            #pragma unroll
            for (int r = 0; r < 4; ++r) {
                const int row = rowb + r;
                if (row < M)
                    H[(size_t)row * D + col] = f2bf(fmaxf(acc[mf][nf][r] + bv, 0.f));
            }
        }
    }
}

// ---------------------------------------------------------------------------
// out MFMA: out = h1 @ W2t^T + b2 + x   (f32 out)
// 512 threads / 8 waves, 128x64 tile, 2-phase pipeline, rule-#21 swizzle,
// XCD-bijective swizzle, x reg-prefetch.  (verified R18)
// ---------------------------------------------------------------------------
__global__ __launch_bounds__(512)
void mfma_gemm_kernel(const ushort* __restrict__ A, const ushort* __restrict__ Bt,
                      const float* __restrict__ bias, const float* __restrict__ xres,
                      float* __restrict__ Cout, int M) {
    __shared__ ushort As[2][128 * 64];
    __shared__ ushort Bs[2][64 * 64];
    const int tid  = threadIdx.x;
    const int lane = tid & 63;
    const int wid  = tid >> 6;        // 0..7
    const int wm   = wid >> 1;        // 0..3
    const int wn   = wid & 1;         // 0..1

    const int l = blockIdx.y * gridDim.x + blockIdx.x;
    const int cpx = (gridDim.x * gridDim.y) >> 3;
    const int t_ = (l & 7) * cpx + (l >> 3);
    const int n0 = (t_ & 7) * 64;
    const int m0 = (t_ >> 3) * 128;

    const int sr = lane >> 3;         // 0..7
    const int sc = lane & 7;          // chunk 0..7

    f32x4 acc[2][2] = {};
    constexpr int KTILES = D / 64;

    auto stage = [&](int buf, int t) {   // 3 gloads per wave
        #pragma unroll
        for (int j = 0; j < 2; ++j) {    // A: wave rows [wid*16, +16)
            const int r  = wid * 16 + j * 8 + sr;
            const int gm = (m0 + r < M) ? (m0 + r) : (M - 1);
            const int cs = (sc ^ (r & 7)) * 8;
            const int rowbase = wid * 16 + j * 8;
            gload16(A + (size_t)gm * D + t * 64 + cs, &As[buf][rowbase * 64]);
        }
        {                                // B: wave rows [wid*8, +8)
            const int r  = wid * 8 + sr;
            const int cs = (sc ^ (r & 7)) * 8;
            const int rowbase = wid * 8;
            gload16(Bt + (size_t)(n0 + r) * D + t * 64 + cs, &Bs[buf][rowbase * 64]);
        }
    };

    stage(0, 0);

    // x-residual prefetch (independent; hides under the K-loop)
    float xv[2][2][4];
    #pragma unroll
    for (int mf = 0; mf < 2; ++mf) {
        const int rowb = m0 + wm * 32 + mf * 16 + ((lane >> 4) << 2);
        #pragma unroll
        for (int nf = 0; nf < 2; ++nf) {
            const int col = n0 + wn * 32 + nf * 16 + (lane & 15);
            #pragma unroll
            for (int r = 0; r < 4; ++r) {
                const int row = (rowb + r < M) ? (rowb + r) : (M - 1);
                xv[mf][nf][r] = xres[(size_t)row * D + col];
            }
        }
    }

    __syncthreads();

    for (int t = 0; t < KTILES; ++t) {
        const int cur = t & 1;
        if (t + 1 < KTILES) stage(cur ^ 1, t + 1);
        #pragma unroll
        for (int kk = 0; kk < 2; ++kk) {
            const int kc = kk * 4 + (lane >> 4);
            short8 af[2], bfr[2];
            #pragma unroll
            for (int mf = 0; mf < 2; ++mf) {
                const int ar = wm * 32 + mf * 16 + (lane & 15);
                af[mf] = *reinterpret_cast<const short8*>(
                    &As[cur][ar * 64 + ((kc ^ (ar & 7)) * 8)]);
            }
            #pragma unroll
            for (int nf = 0; nf < 2; ++nf) {
                const int br = wn * 32 + nf * 16 + (lane & 15);
                bfr[nf] = *reinterpret_cast<const short8*>(
                    &Bs[cur][br * 64 + ((kc ^ (br & 7)) * 8)]);
            }
            #pragma unroll
            for (int mf = 0; mf < 2; ++mf)
                #pragma unroll
                for (int nf = 0; nf < 2; ++nf)
                    acc[mf][nf] = __builtin_amdgcn_mfma_f32_16x16x32_bf16(
                        af[mf], bfr[nf], acc[mf][nf], 0, 0, 0);
        }
        __syncthreads();
    }

    #pragma unroll
    for (int mf = 0; mf < 2; ++mf) {
        const int rowb = m0 + wm * 32 + mf * 16 + ((lane >> 4) << 2);
        #pragma unroll
        for (int nf = 0; nf < 2; ++nf) {
            const int col = n0 + wn * 32 + nf * 16 + (lane & 15);
            const float bv = bias[col];
            #pragma unroll
            for (int r = 0; r < 4; ++r) {
                const int row = rowb + r;
                if (row < M)
                    Cout[(size_t)row * D + col] =
                        acc[mf][nf][r] + bv + xv[mf][nf][r];
            }
        }
    }
}

extern "C" void kernel_launch(void* const* d_in, const int* in_sizes, int n_in,
                              void* d_out, int out_size, void* d_ws, size_t ws_size,
                              hipStream_t stream) {
    const float* x      = (const float*)d_in[0];
    const int*   edge_index = (const int*)d_in[2];
    const float* rbf    = (const float*)d_in[3];
    const float* ang    = (const float*)d_in[4];
    const float* W_edge = (const float*)d_in[5];
    const float* b_edge = (const float*)d_in[6];
    const float* W1     = (const float*)d_in[7];
    const float* b1     = (const float*)d_in[8];
    const float* W2     = (const float*)d_in[9];
    const float* b2     = (const float*)d_in[10];
    float* out = (float*)d_out;

    char* w = (char*)d_ws;
    ushort* aggX = (ushort*)w;                       //  2,560,000 B [NN][128]
    ushort* W2t  = (ushort*)(w + 2560000);           //    524,288 B
    ushort* WcT  = (ushort*)(w + 3084288);           //    131,072 B [512][128]
    int*    deg  = (int*)(w + 3215360);              //     40,000 B
    float*  part = (float*)(w + 3255360);            //  1,327,104 B
    int*    ell  = (int*)(w + 4582464);              //  3,840,000 B
    ushort* h1   = (ushort*)(w + 3255360);           // 10,240,000 B (aliases part+ell)

    prep1_kernel<<<1640, 256, 0, stream>>>(W_edge, b_edge, W1, W2, part, W2t, deg);
    prep2_kernel<<<881, 256, 0, stream>>>(part, edge_index, WcT, deg, ell);
    gather_agg_kernel<<<NN / 4, 256, 0, stream>>>(deg, ell, rbf, ang, aggX);

    dim3 ggrid(D / 64, (NN + 127) / 128);   // 8 x 79 = 632 blocks, %8==0
    h1_mfma_kernel<<<ggrid, 512, 0, stream>>>(aggX, WcT, b1, h1, NN);
    mfma_gemm_kernel<<<ggrid, 512, 0, stream>>>(h1, W2t, b2, x, out, NN);
}

// Round 20
// 63.428 us; speedup vs baseline: 1.0754x; 1.0145x over previous
//
#include <hip/hip_runtime.h>

constexpr int NN = 10000;
constexpr int NE = 160000;
constexpr int D  = 512;
constexpr int KC = 8;      // wcomb split-K chunks (K=512 -> 8 x 64)
constexpr int MAXDEG = 96; // ELL width; mean deg 16

typedef __attribute__((ext_vector_type(8))) short short8;   // 8 bf16 (4 VGPRs)
typedef __attribute__((ext_vector_type(4))) float f32x4;    // MFMA C/D

static __device__ __forceinline__ ushort f2bf(float f) {
    union { float f; unsigned u; } v; v.f = f;
    unsigned r = (v.u + 0x7FFFu + ((v.u >> 16) & 1u)) >> 16;   // RNE
    return (ushort)r;
}

typedef __attribute__((address_space(3))) unsigned int lds_uint;
typedef const __attribute__((address_space(1))) unsigned int glb_uint;
static __device__ __forceinline__ void gload16(const ushort* g, ushort* l) {
    __builtin_amdgcn_global_load_lds((glb_uint*)g, (lds_uint*)l, 16, 0, 0);
}

// ---------------------------------------------------------------------------
// prep1: blocks [0,1344) wcomb split-K partials | [1344,1600) W2 transpose |
//        [1600,1640) zero deg.  (verified R10)
// ---------------------------------------------------------------------------
__global__ __launch_bounds__(256)
void prep1_kernel(const float* __restrict__ We, const float* __restrict__ be,
                  const float* __restrict__ W1, const float* __restrict__ W2,
                  float* __restrict__ part, ushort* __restrict__ W2t,
                  int* __restrict__ deg) {
    __shared__ float tile[32][33];
    const int b   = blockIdx.x;
    const int tid = threadIdx.x;

    if (b < 1344) {
        const int c  = (b & 7) * 64 + (tid & 63);
        const int r  = ((b >> 3) % 21) * 4 + (tid >> 6);
        const int kc = b / 168;
        if (r > 80) return;
        const float* arow = (r < 80) ? (We + (size_t)r * D) : be;
        const int k0 = kc * 64;
        float s = 0.f;
        #pragma unroll
        for (int k = 0; k < 64; k += 4) {
            float4 a = *reinterpret_cast<const float4*>(&arow[k0 + k]);
            s += a.x * W1[(size_t)(k0 + k    ) * D + c];
            s += a.y * W1[(size_t)(k0 + k + 1) * D + c];
            s += a.z * W1[(size_t)(k0 + k + 2) * D + c];
            s += a.w * W1[(size_t)(k0 + k + 3) * D + c];
        }
        part[((size_t)kc * 81 + r) * D + c] = s;
    } else if (b < 1600) {
        const int t  = b - 1344;
        const int bx = (t & 15) * 32;
        const int by = (t >> 4) * 32;
        const int tx = tid & 31;
        const int ty = tid >> 5;
        #pragma unroll
        for (int i = 0; i < 4; ++i)
            tile[ty + 8 * i][tx] = W2[(size_t)(by + ty + 8 * i) * D + bx + tx];
        __syncthreads();
        #pragma unroll
        for (int i = 0; i < 4; ++i)
            W2t[(size_t)(bx + ty + 8 * i) * D + by + tx] = f2bf(tile[tx][ty + 8 * i]);
    } else {
        const int i = (b - 1600) * 256 + tid;
        if (i < NN) deg[i] = 0;
    }
}

// ---------------------------------------------------------------------------
// prep2: blocks [0,256) wcomb_reduce -> WcT | [256,881) fill_ell  (verified)
// ---------------------------------------------------------------------------
__global__ __launch_bounds__(256)
void prep2_kernel(const float* __restrict__ part, const int* __restrict__ row,
                  ushort* __restrict__ WcT, int* __restrict__ deg,
                  int* __restrict__ ell) {
    const int b   = blockIdx.x;
    const int tid = threadIdx.x;
    if (b < 256) {
        const int i = b * 256 + tid;
        const int k = i >> 9;
        const int c = i & 511;
        float s = 0.f;
        if (k <= 80) {
            #pragma unroll
            for (int kc = 0; kc < KC; ++kc)
                s += part[((size_t)kc * 81 + k) * D + c];
        }
        WcT[(size_t)c * 128 + k] = f2bf(s);
    } else {
        const int e = (b - 256) * 256 + tid;
        if (e < NE) {
            int r = row[e];
            int slot = atomicAdd(&deg[r], 1);
            if (slot < MAXDEG) ell[r * MAXDEG + slot] = e;
        }
    }
}

// ---------------------------------------------------------------------------
// gather (R20): wave per node, float4 lanes. 4 x 16-lane groups; group eg
// handles edge en[i+eg]; lane reads float4 of 4 feature cols -> 4 edges per
// load instruction (was 1), 4x fewer load slots per byte. 2-step shfl_xor
// float4 butterfly merges group partials. Emits bf16 aggX[n][128]:
//   cols 0..63 rbf sums, 64..79 ang sums, 80 = cnt, 81..127 = 0
// ---------------------------------------------------------------------------
__global__ __launch_bounds__(256)
void gather_agg_kernel(const int* __restrict__ deg, const int* __restrict__ ell,
                       const float* __restrict__ rbf, const float* __restrict__ ang,
                       ushort* __restrict__ aggX) {
    const int wv   = threadIdx.x >> 6;
    const int lane = threadIdx.x & 63;
    const int eg   = lane >> 4;       // edge group 0..3
    const int fl   = lane & 15;       // float4 slot: cols fl*4..fl*4+3
    const int n    = blockIdx.x * 4 + wv;
    if (n >= NN) return;
    int d = deg[n];
    if (d > MAXDEG) d = MAXDEG;
    const int* en = ell + (size_t)n * MAXDEG;

    float4 s1 = make_float4(0.f, 0.f, 0.f, 0.f);
    float4 s2 = make_float4(0.f, 0.f, 0.f, 0.f);

    int i = 0;
    for (; i + 8 <= d; i += 8) {      // 8 edges per iter (2 per group)
        const int ea = en[i + eg];
        const int eb = en[i + 4 + eg];
        const float4 va = *reinterpret_cast<const float4*>(&rbf[ea * 64 + fl * 4]);
        const float4 vb = *reinterpret_cast<const float4*>(&rbf[eb * 64 + fl * 4]);
        if (fl < 4) {
            const float4 aa = *reinterpret_cast<const float4*>(&ang[ea * 16 + fl * 4]);
            const float4 ab = *reinterpret_cast<const float4*>(&ang[eb * 16 + fl * 4]);
            s2.x += aa.x + ab.x; s2.y += aa.y + ab.y;
            s2.z += aa.z + ab.z; s2.w += aa.w + ab.w;
        }
        s1.x += va.x + vb.x; s1.y += va.y + vb.y;
        s1.z += va.z + vb.z; s1.w += va.w + vb.w;
    }
    for (; i < d; i += 4) {           // tail, 4 edges per iter (guarded)
        if (i + eg < d) {
            const int e = en[i + eg];
            const float4 v = *reinterpret_cast<const float4*>(&rbf[e * 64 + fl * 4]);
            if (fl < 4) {
                const float4 a = *reinterpret_cast<const float4*>(&ang[e * 16 + fl * 4]);
                s2.x += a.x; s2.y += a.y; s2.z += a.z; s2.w += a.w;
            }
            s1.x += v.x; s1.y += v.y; s1.z += v.z; s1.w += v.w;
        }
    }

    // butterfly-reduce the 4 edge groups (lanes fl, fl+16, fl+32, fl+48)
    #pragma unroll
    for (int dx = 16; dx < 64; dx <<= 1) {
        s1.x += __shfl_xor(s1.x, dx, 64);
        s1.y += __shfl_xor(s1.y, dx, 64);
        s1.z += __shfl_xor(s1.z, dx, 64);
        s1.w += __shfl_xor(s1.w, dx, 64);
        s2.x += __shfl_xor(s2.x, dx, 64);
        s2.y += __shfl_xor(s2.y, dx, 64);
        s2.z += __shfl_xor(s2.z, dx, 64);
        s2.w += __shfl_xor(s2.w, dx, 64);
    }

    if (eg == 0) {                    // lanes 0..15 write the full row
        ushort4 w;
        w.x = f2bf(s1.x); w.y = f2bf(s1.y); w.z = f2bf(s1.z); w.w = f2bf(s1.w);
        *reinterpret_cast<ushort4*>(&aggX[(size_t)n * 128 + fl * 4]) = w;

        float4 h = make_float4(0.f, 0.f, 0.f, 0.f);
        if (fl < 4) h = s2;                       // ang cols 64..79
        else if (fl == 4) h.x = (float)d;         // cnt at col 80
        ushort4 w2;
        w2.x = f2bf(h.x); w2.y = f2bf(h.y); w2.z = f2bf(h.z); w2.w = f2bf(h.w);
        *reinterpret_cast<ushort4*>(&aggX[(size_t)n * 128 + 64 + fl * 4]) = w2;
    }
}

// ---------------------------------------------------------------------------
// h1 MFMA (single K-tile, K=128): h1 = bf16(relu(aggX @ WcT^T + b1))
// 512 threads / 8 waves, 128x64 tile, grid 8 x 79.  (verified R19)
// ---------------------------------------------------------------------------
__global__ __launch_bounds__(512)
void h1_mfma_kernel(const ushort* __restrict__ A, const ushort* __restrict__ Bt,
                    const float* __restrict__ b1, ushort* __restrict__ H, int M) {
    __shared__ ushort As[128 * 128];   // 32 KB
    __shared__ ushort Bs[64 * 128];    // 16 KB
    const int tid  = threadIdx.x;
    const int lane = tid & 63;
    const int wid  = tid >> 6;        // 0..7
    const int wm   = wid >> 1;        // 0..3
    const int wn   = wid & 1;         // 0..1

    const int l = blockIdx.y * gridDim.x + blockIdx.x;
    const int cpx = (gridDim.x * gridDim.y) >> 3;
    const int t_ = (l & 7) * cpx + (l >> 3);
    const int n0 = (t_ & 7) * 64;
    const int m0 = (t_ >> 3) * 128;

    const int rg = lane >> 4;         // 0..3
    const int ch = lane & 15;         // 16B chunk 0..15

    f32x4 acc[2][2] = {};

    #pragma unroll
    for (int j = 0; j < 4; ++j) {
        const int r  = wid * 16 + j * 4 + rg;
        const int gm = (m0 + r < M) ? (m0 + r) : (M - 1);
        const int cs = (ch ^ (r & 7)) * 8;
        const int rowbase = wid * 16 + j * 4;
        gload16(A + (size_t)gm * 128 + cs, &As[rowbase * 128]);
    }
    #pragma unroll
    for (int j = 0; j < 2; ++j) {
        const int r  = wid * 8 + j * 4 + rg;
        const int cs = (ch ^ (r & 7)) * 8;
        const int rowbase = wid * 8 + j * 4;
        gload16(Bt + (size_t)(n0 + r) * 128 + cs, &Bs[rowbase * 128]);
    }
    __syncthreads();

    #pragma unroll
    for (int kk = 0; kk < 4; ++kk) {
        const int kc = kk * 4 + (lane >> 4);
        short8 af[2], bfr[2];
        #pragma unroll
        for (int mf = 0; mf < 2; ++mf) {
            const int ar = wm * 32 + mf * 16 + (lane & 15);
            af[mf] = *reinterpret_cast<const short8*>(
                &As[ar * 128 + ((kc ^ (ar & 7)) * 8)]);
        }
        #pragma unroll
        for (int nf = 0; nf < 2; ++nf) {
            const int br = wn * 32 + nf * 16 + (lane & 15);
            bfr[nf] = *reinterpret_cast<const short8*>(
                &Bs[br * 128 + ((kc ^ (br & 7)) * 8)]);
        }
        #pragma unroll
        for (int mf = 0; mf < 2; ++mf)
            #pragma unroll
            for (int nf = 0; nf < 2; ++nf)
                acc[mf][nf] = __builtin_amdgcn_mfma_f32_16x16x32_bf16(
                    af[mf], bfr[nf], acc[mf][nf], 0, 0, 0);
    }

    #pragma unroll
    for (int mf = 0; mf < 2; ++mf) {
        const int rowb = m0 + wm * 32 + mf * 16 + ((lane >> 4) << 2);
        #pragma unroll
        for (int nf = 0; nf < 2; ++nf) {
            const int col = n0 + wn * 32 + nf * 16 + (lane & 15);
            const float bv = b1[col];
            #pragma unroll
            for (int r = 0; r < 4; ++r) {
                const int row = rowb + r;
                if (row < M)
                    H[(size_t)row * D + col] = f2bf(fmaxf(acc[mf][nf][r] + bv, 0.f));
            }
        }
    }
}

// ---------------------------------------------------------------------------
// out MFMA: out = h1 @ W2t^T + b2 + x   (f32 out)
// 512 threads / 8 waves, 128x64 tile, 2-phase pipeline, rule-#21 swizzle,
// XCD-bijective swizzle, x reg-prefetch.  (verified R18)
// ---------------------------------------------------------------------------
__global__ __launch_bounds__(512)
void mfma_gemm_kernel(const ushort* __restrict__ A, const ushort* __restrict__ Bt,
                      const float* __restrict__ bias, const float* __restrict__ xres,
                      float* __restrict__ Cout, int M) {
    __shared__ ushort As[2][128 * 64];
    __shared__ ushort Bs[2][64 * 64];
    const int tid  = threadIdx.x;
    const int lane = tid & 63;
    const int wid  = tid >> 6;        // 0..7
    const int wm   = wid >> 1;        // 0..3
    const int wn   = wid & 1;         // 0..1

    const int l = blockIdx.y * gridDim.x + blockIdx.x;
    const int cpx = (gridDim.x * gridDim.y) >> 3;
    const int t_ = (l & 7) * cpx + (l >> 3);
    const int n0 = (t_ & 7) * 64;
    const int m0 = (t_ >> 3) * 128;

    const int sr = lane >> 3;         // 0..7
    const int sc = lane & 7;          // chunk 0..7

    f32x4 acc[2][2] = {};
    constexpr int KTILES = D / 64;

    auto stage = [&](int buf, int t) {
        #pragma unroll
        for (int j = 0; j < 2; ++j) {
            const int r  = wid * 16 + j * 8 + sr;
            const int gm = (m0 + r < M) ? (m0 + r) : (M - 1);
            const int cs = (sc ^ (r & 7)) * 8;
            const int rowbase = wid * 16 + j * 8;
            gload16(A + (size_t)gm * D + t * 64 + cs, &As[buf][rowbase * 64]);
        }
        {
            const int r  = wid * 8 + sr;
            const int cs = (sc ^ (r & 7)) * 8;
            const int rowbase = wid * 8;
            gload16(Bt + (size_t)(n0 + r) * D + t * 64 + cs, &Bs[buf][rowbase * 64]);
        }
    };

    stage(0, 0);

    float xv[2][2][4];
    #pragma unroll
    for (int mf = 0; mf < 2; ++mf) {
        const int rowb = m0 + wm * 32 + mf * 16 + ((lane >> 4) << 2);
        #pragma unroll
        for (int nf = 0; nf < 2; ++nf) {
            const int col = n0 + wn * 32 + nf * 16 + (lane & 15);
            #pragma unroll
            for (int r = 0; r < 4; ++r) {
                const int row = (rowb + r < M) ? (rowb + r) : (M - 1);
                xv[mf][nf][r] = xres[(size_t)row * D + col];
            }
        }
    }

    __syncthreads();

    for (int t = 0; t < KTILES; ++t) {
        const int cur = t & 1;
        if (t + 1 < KTILES) stage(cur ^ 1, t + 1);
        #pragma unroll
        for (int kk = 0; kk < 2; ++kk) {
            const int kc = kk * 4 + (lane >> 4);
            short8 af[2], bfr[2];
            #pragma unroll
            for (int mf = 0; mf < 2; ++mf) {
                const int ar = wm * 32 + mf * 16 + (lane & 15);
                af[mf] = *reinterpret_cast<const short8*>(
                    &As[cur][ar * 64 + ((kc ^ (ar & 7)) * 8)]);
            }
            #pragma unroll
            for (int nf = 0; nf < 2; ++nf) {
                const int br = wn * 32 + nf * 16 + (lane & 15);
                bfr[nf] = *reinterpret_cast<const short8*>(
                    &Bs[cur][br * 64 + ((kc ^ (br & 7)) * 8)]);
            }
            #pragma unroll
            for (int mf = 0; mf < 2; ++mf)
                #pragma unroll
                for (int nf = 0; nf < 2; ++nf)
                    acc[mf][nf] = __builtin_amdgcn_mfma_f32_16x16x32_bf16(
                        af[mf], bfr[nf], acc[mf][nf], 0, 0, 0);
        }
        __syncthreads();
    }

    #pragma unroll
    for (int mf = 0; mf < 2; ++mf) {
        const int rowb = m0 + wm * 32 + mf * 16 + ((lane >> 4) << 2);
        #pragma unroll
        for (int nf = 0; nf < 2; ++nf) {
            const int col = n0 + wn * 32 + nf * 16 + (lane & 15);
            const float bv = bias[col];
            #pragma unroll
            for (int r = 0; r < 4; ++r) {
                const int row = rowb + r;
                if (row < M)
                    Cout[(size_t)row * D + col] =
                        acc[mf][nf][r] + bv + xv[mf][nf][r];
            }
        }
    }
}

extern "C" void kernel_launch(void* const* d_in, const int* in_sizes, int n_in,
                              void* d_out, int out_size, void* d_ws, size_t ws_size,
                              hipStream_t stream) {
    const float* x      = (const float*)d_in[0];
    const int*   edge_index = (const int*)d_in[2];
    const float* rbf    = (const float*)d_in[3];
    const float* ang    = (const float*)d_in[4];
    const float* W_edge = (const float*)d_in[5];
    const float* b_edge = (const float*)d_in[6];
    const float* W1     = (const float*)d_in[7];
    const float* b1     = (const float*)d_in[8];
    const float* W2     = (const float*)d_in[9];
    const float* b2     = (const float*)d_in[10];
    float* out = (float*)d_out;

    char* w = (char*)d_ws;
    ushort* aggX = (ushort*)w;                       //  2,560,000 B [NN][128]
    ushort* W2t  = (ushort*)(w + 2560000);           //    524,288 B
    ushort* WcT  = (ushort*)(w + 3084288);           //    131,072 B [512][128]
    int*    deg  = (int*)(w + 3215360);              //     40,000 B
    float*  part = (float*)(w + 3255360);            //  1,327,104 B
    int*    ell  = (int*)(w + 4582464);              //  3,840,000 B
    ushort* h1   = (ushort*)(w + 3255360);           // 10,240,000 B (aliases part+ell)

    prep1_kernel<<<1640, 256, 0, stream>>>(W_edge, b_edge, W1, W2, part, W2t, deg);
    prep2_kernel<<<881, 256, 0, stream>>>(part, edge_index, WcT, deg, ell);
    gather_agg_kernel<<<NN / 4, 256, 0, stream>>>(deg, ell, rbf, ang, aggX);

    dim3 ggrid(D / 64, (NN + 127) / 128);   // 8 x 79 = 632 blocks, %8==0
    h1_mfma_kernel<<<ggrid, 512, 0, stream>>>(aggX, WcT, b1, h1, NN);
    mfma_gemm_kernel<<<ggrid, 512, 0, stream>>>(h1, W2t, b2, x, out, NN);
}